// Round 12
// baseline (228.023 us; speedup 1.0000x reference)
//
#include <hip/hip_runtime.h>
#include <hip/hip_fp16.h>

#define IN_F 128
#define OUT_F 32
#define R_NODES 256          // dst nodes per bucket (8 bits)
#define RSHIFT 8
#define RMASK 255
#define BKT_CAP 7168         // multiple of 16; Poisson(4092)+padding+9sigma
#define OVF_CAP 4096
#define EPB 8192             // edges per build sub-block
#define MAXNB 512            // max buckets => n_nodes <= 131072
#define SENT 0xFFFFFFFFu     // pad sentinel in bkt (skipped by sortgather)

// ---------------------------------------------------------------------------
// Mega kernel: CU-paired build || linear. bid<n_bbl -> build; bid in
// [256,256+n_lbl) -> linear; else exit. Under round-robin block->CU
// assignment, CU c hosts build block c AND linear block 256+c (round-11
// lesson: parity interleave pairs build-with-build on even CUs).
// Build sweeps are int4-ILP-batched: 8 edges/thread, 4 independent 16B
// loads up front, then 8 fire-and-forget atomics (round-11 lesson: the
// serial load->atomic chain at ~800cyc x8 was the 74us critical path).
// ---------------------------------------------------------------------------
struct BuildSmem {
    unsigned sorted[EPB];        // 32 KB
    unsigned short binof[EPB];   // 16 KB
    int hist[MAXNB];             // count, then cursor
    int lbase[MAXNB];
    int gbase[MAXNB];
    int wsum[16];
};
struct LinSmem { float w[IN_F * OUT_F]; };
union MegaSmem { BuildSmem b; LinSmem l; };

__global__ __launch_bounds__(1024) void mega_kernel(
    const int* __restrict__ src, const int* __restrict__ dst,
    const float* __restrict__ feat, const float* __restrict__ weight,
    int* __restrict__ out_cnt, int* __restrict__ in_cnt,
    int* __restrict__ gcur, unsigned* __restrict__ bkt,
    int* __restrict__ ovf, int* __restrict__ ovf_cnt,
    __half* __restrict__ tmp, int n_edges, int n_nodes,
    int n_bbl, int n_lbl, int lstart) {

    __shared__ MegaSmem sm;
    int tid = threadIdx.x;
    int bid = blockIdx.x;

    if (bid < n_bbl) {
        // ================= BUILD =================
        int sub = bid;
        int e0 = sub * EPB;
        int ecnt = min(EPB, n_edges - e0);
        bool full = (ecnt == EPB);

        if (tid < MAXNB) sm.b.hist[tid] = 0;
        __syncthreads();

        // sweep 1: vector loads + batched atomics
        if (full) {
            const int4* s4 = (const int4*)(src + e0) + tid * 2;
            const int4* d4 = (const int4*)(dst + e0) + tid * 2;
            int4 sa = s4[0], sb = s4[1];
            int4 da = d4[0], db = d4[1];
            int ss[8] = {sa.x, sa.y, sa.z, sa.w, sb.x, sb.y, sb.z, sb.w};
            int dd[8] = {da.x, da.y, da.z, da.w, db.x, db.y, db.z, db.w};
#pragma unroll
            for (int r = 0; r < 8; ++r) atomicAdd(&out_cnt[ss[r]], 1);
#pragma unroll
            for (int r = 0; r < 8; ++r) atomicAdd(&sm.b.hist[dd[r] >> RSHIFT], 1);
        } else {
            for (int k = tid; k < ecnt; k += 1024) {
                int e = e0 + k;
                atomicAdd(&out_cnt[src[e]], 1);
                atomicAdd(&sm.b.hist[dst[e] >> RSHIFT], 1);
            }
        }
        __syncthreads();

        // block scan + line-aligned chunk reservation
        int cnt = (tid < MAXNB) ? sm.b.hist[tid] : 0;
        int lane = tid & 63, wid = tid >> 6;
        int scan = cnt;
        for (int off = 1; off < 64; off <<= 1) {
            int v = __shfl_up(scan, off, 64);
            if (lane >= off) scan += v;
        }
        if (lane == 63) sm.b.wsum[wid] = scan;
        __syncthreads();
        int woff = 0;
        for (int w = 0; w < wid; ++w) woff += sm.b.wsum[w];
        int excl = woff + scan - cnt;
        if (tid < MAXNB) {
            sm.b.lbase[tid] = excl;
            sm.b.hist[tid]  = excl;         // becomes insertion cursor
            int res = (cnt + 15) & ~15;     // whole 64B lines
            if (cnt > 0) sm.b.gbase[tid] = atomicAdd(&gcur[tid], res);
        }
        __syncthreads();

        // sweep 2: L2-hot vector re-read -> LDS counting-sort
        if (full) {
            const int4* s4 = (const int4*)(src + e0) + tid * 2;
            const int4* d4 = (const int4*)(dst + e0) + tid * 2;
            int4 sa = s4[0], sb = s4[1];
            int4 da = d4[0], db = d4[1];
            int ss[8] = {sa.x, sa.y, sa.z, sa.w, sb.x, sb.y, sb.z, sb.w};
            int dd[8] = {da.x, da.y, da.z, da.w, db.x, db.y, db.z, db.w};
#pragma unroll
            for (int r = 0; r < 8; ++r) {
                int bin = dd[r] >> RSHIFT;
                int idx = atomicAdd(&sm.b.hist[bin], 1);
                sm.b.sorted[idx] = ((unsigned)ss[r] << RSHIFT) | (unsigned)(dd[r] & RMASK);
                sm.b.binof[idx]  = (unsigned short)bin;
            }
        } else {
            for (int k = tid; k < ecnt; k += 1024) {
                int e = e0 + k;
                int s = src[e], d = dst[e];
                int bin = d >> RSHIFT;
                int idx = atomicAdd(&sm.b.hist[bin], 1);
                sm.b.sorted[idx] = ((unsigned)s << RSHIFT) | (unsigned)(d & RMASK);
                sm.b.binof[idx]  = (unsigned short)bin;
            }
        }
        __syncthreads();

        // sweep 3: dense line-aligned flush (ILP batch of 4) + sentinel pads
        {
            int i = tid * 4;
            for (; i + 4 <= ecnt; i += 4096) {
                uint4 v = *(const uint4*)&sm.b.sorted[i];      // ds_read_b128
                ushort4 bn = *(const ushort4*)&sm.b.binof[i];
                unsigned vv[4] = {v.x, v.y, v.z, v.w};
                int bb[4] = {bn.x, bn.y, bn.z, bn.w};
#pragma unroll
                for (int r = 0; r < 4; ++r) {
                    int gpos = sm.b.gbase[bb[r]] + (i + r - sm.b.lbase[bb[r]]);
                    if (gpos < BKT_CAP) {
                        bkt[(size_t)bb[r] * BKT_CAP + gpos] = vv[r];
                    } else {
                        int d = bb[r] * R_NODES + (int)(vv[r] & RMASK);
                        atomicAdd(&in_cnt[d], 1);
                        int o = atomicAdd(ovf_cnt, 1);
                        if (o < OVF_CAP) {
                            ovf[2 * o]     = (int)(vv[r] >> RSHIFT);
                            ovf[2 * o + 1] = d;
                        }
                    }
                }
            }
            for (int k = i; k < ecnt; ++k) {    // tail (only non-full block)
                unsigned v = sm.b.sorted[k];
                int bin = sm.b.binof[k];
                int gpos = sm.b.gbase[bin] + (k - sm.b.lbase[bin]);
                if (gpos < BKT_CAP) {
                    bkt[(size_t)bin * BKT_CAP + gpos] = v;
                } else {
                    int d = bin * R_NODES + (int)(v & RMASK);
                    atomicAdd(&in_cnt[d], 1);
                    int o = atomicAdd(ovf_cnt, 1);
                    if (o < OVF_CAP) {
                        ovf[2 * o]     = (int)(v >> RSHIFT);
                        ovf[2 * o + 1] = d;
                    }
                }
            }
        }
        for (int bin = tid; bin < MAXNB; bin += 1024) {
            int bc  = sm.b.hist[bin] - sm.b.lbase[bin];
            int res = (bc + 15) & ~15;
            for (int p = bc; p < res; ++p) {
                int gpos = sm.b.gbase[bin] + p;
                if (gpos < BKT_CAP) bkt[(size_t)bin * BKT_CAP + gpos] = SENT;
            }
        }
    } else if (bid >= lstart && bid - lstart < n_lbl) {
        // ================= LINEAR (unscaled feat @ W -> fp16 tmp) =========
        int sub = bid - lstart;
        if (tid < 1024) ((float4*)sm.l.w)[tid] = ((const float4*)weight)[tid];
        __syncthreads();

        int q  = tid >> 3;
        int cg = tid & 7;
        int row0 = sub * 512 + q * 4;
        if (row0 >= n_nodes) return;
        int rmax = n_nodes - row0;
        if (rmax > 4) rmax = 4;

        const float4* feat4 = (const float4*)feat;
        float4 acc[4];
#pragma unroll
        for (int r = 0; r < 4; ++r) acc[r] = make_float4(0.f, 0.f, 0.f, 0.f);

        for (int k4 = 0; k4 < IN_F / 4; ++k4) {
            float4 wv0 = *(const float4*)&sm.l.w[(4 * k4 + 0) * OUT_F + 4 * cg];
            float4 wv1 = *(const float4*)&sm.l.w[(4 * k4 + 1) * OUT_F + 4 * cg];
            float4 wv2 = *(const float4*)&sm.l.w[(4 * k4 + 2) * OUT_F + 4 * cg];
            float4 wv3 = *(const float4*)&sm.l.w[(4 * k4 + 3) * OUT_F + 4 * cg];
#pragma unroll
            for (int r = 0; r < 4; ++r) {
                int rr = (r < rmax) ? r : 0;
                float4 f = feat4[(size_t)(row0 + rr) * (IN_F / 4) + k4];
                acc[r].x += f.x * wv0.x + f.y * wv1.x + f.z * wv2.x + f.w * wv3.x;
                acc[r].y += f.x * wv0.y + f.y * wv1.y + f.z * wv2.y + f.w * wv3.y;
                acc[r].z += f.x * wv0.z + f.y * wv1.z + f.z * wv2.z + f.w * wv3.z;
                acc[r].w += f.x * wv0.w + f.y * wv1.w + f.z * wv2.w + f.w * wv3.w;
            }
        }

#pragma unroll
        for (int r = 0; r < 4; ++r) {
            if (r < rmax) {
                union { __half h[4]; uint2 u; } pk;
                pk.h[0] = __float2half(acc[r].x);
                pk.h[1] = __float2half(acc[r].y);
                pk.h[2] = __float2half(acc[r].z);
                pk.h[3] = __float2half(acc[r].w);
                *(uint2*)&tmp[(size_t)(row0 + r) * OUT_F + 4 * cg] = pk.u;
            }
        }
    }
    // else: idle pad block, exit
}

// ---------------------------------------------------------------------------
// Fold src-degree scale into tmp in-place (out_cnt final after mega).
// ---------------------------------------------------------------------------
__global__ __launch_bounds__(256) void scale_tmp(__half* __restrict__ tmp,
                                                 const int* __restrict__ out_cnt,
                                                 int n_nodes) {
    int t = blockIdx.x * 256 + threadIdx.x;
    int node = t >> 2;
    if (node >= n_nodes) return;
    float sc = rsqrtf(fmaxf((float)out_cnt[node], 1.0f));
    uint4* p = (uint4*)(tmp + (size_t)node * OUT_F) + (t & 3);
    uint4 v = *p;
    __half2* h = (__half2*)&v;
#pragma unroll
    for (int i = 0; i < 4; ++i) {
        float2 f = __half22float2(h[i]);
        f.x *= sc; f.y *= sc;
        h[i] = __float22half2_rn(f);
    }
    *p = v;
}

// ---------------------------------------------------------------------------
// Fused sort+gather+overflow: one 1024-thread block per 256-node bucket.
// uint4 staging (ecnt is a 16-multiple by construction). Gather inner loop:
// pre-scaled fp16 row loads + fp32 adds, 8-way ILP, no atomics.
// ---------------------------------------------------------------------------
__global__ __launch_bounds__(1024) void sortgather_kernel(
    const unsigned* __restrict__ bkt, const int* __restrict__ gcur,
    const int* __restrict__ in_cnt,
    const int* __restrict__ ovf, const int* __restrict__ ovf_cnt,
    const __half* __restrict__ tmp, float* __restrict__ out, int n_nodes) {

    __shared__ unsigned ent[BKT_CAP];   // 28 KB
    __shared__ unsigned srt[BKT_CAP];   // 28 KB (src ids, node-sorted)
    __shared__ int hist[R_NODES];
    __shared__ int base[R_NODES];
    __shared__ int start[R_NODES];

    int b = blockIdx.x, tid = threadIdx.x;
    int ecnt = min(gcur[b], BKT_CAP);   // multiple of 16
    const unsigned* gb = bkt + (size_t)b * BKT_CAP;

    if (tid < R_NODES) hist[tid] = 0;
    __syncthreads();

    for (int i = tid * 4; i < ecnt; i += 4096) {
        uint4 v = *(const uint4*)(gb + i);
        *(uint4*)(ent + i) = v;
        if (v.x != SENT) atomicAdd(&hist[v.x & RMASK], 1);
        if (v.y != SENT) atomicAdd(&hist[v.y & RMASK], 1);
        if (v.z != SENT) atomicAdd(&hist[v.z & RMASK], 1);
        if (v.w != SENT) atomicAdd(&hist[v.w & RMASK], 1);
    }
    __syncthreads();

    if (tid < 64) {                      // scan 256 bins, 4/lane
        int a0 = hist[4 * tid], a1 = hist[4 * tid + 1];
        int a2 = hist[4 * tid + 2], a3 = hist[4 * tid + 3];
        int s = a0 + a1 + a2 + a3;
        int sc = s;
        for (int off = 1; off < 64; off <<= 1) {
            int v = __shfl_up(sc, off, 64);
            if (tid >= off) sc += v;
        }
        int excl = sc - s;
        base[4 * tid]     = excl;
        base[4 * tid + 1] = excl + a0;
        base[4 * tid + 2] = excl + a0 + a1;
        base[4 * tid + 3] = excl + a0 + a1 + a2;
    }
    __syncthreads();
    if (tid < R_NODES) start[tid] = base[tid];
    __syncthreads();

    for (int i = tid * 4; i < ecnt; i += 4096) {
        uint4 v = *(const uint4*)(ent + i);    // ds_read_b128
        unsigned vv[4] = {v.x, v.y, v.z, v.w};
#pragma unroll
        for (int r = 0; r < 4; ++r) {
            if (vv[r] != SENT) {
                int p = atomicAdd(&base[vv[r] & RMASK], 1);
                srt[p] = vv[r] >> RSHIFT;
            }
        }
    }
    __syncthreads();

    int g = tid >> 5;                    // group 0..31
    int c = tid & 31;                    // column
    int n0 = b * R_NODES;
    int novf = min(*ovf_cnt, OVF_CAP);

    for (int ln = g; ln < R_NODES; ln += 32) {
        int node = n0 + ln;
        if (node >= n_nodes) continue;
        int cnt = hist[ln];
        int st  = start[ln];

        float a0 = 0.f, a1 = 0.f, a2 = 0.f, a3 = 0.f;
        int j = 0;
        for (; j + 8 <= cnt; j += 8) {
            int s0 = (int)srt[st + j + 0], s1 = (int)srt[st + j + 1];
            int s2 = (int)srt[st + j + 2], s3 = (int)srt[st + j + 3];
            int s4 = (int)srt[st + j + 4], s5 = (int)srt[st + j + 5];
            int s6 = (int)srt[st + j + 6], s7 = (int)srt[st + j + 7];
            a0 += __half2float(tmp[(size_t)s0 * OUT_F + c]);
            a1 += __half2float(tmp[(size_t)s1 * OUT_F + c]);
            a2 += __half2float(tmp[(size_t)s2 * OUT_F + c]);
            a3 += __half2float(tmp[(size_t)s3 * OUT_F + c]);
            a0 += __half2float(tmp[(size_t)s4 * OUT_F + c]);
            a1 += __half2float(tmp[(size_t)s5 * OUT_F + c]);
            a2 += __half2float(tmp[(size_t)s6 * OUT_F + c]);
            a3 += __half2float(tmp[(size_t)s7 * OUT_F + c]);
        }
        for (; j < cnt; ++j) {
            int s = (int)srt[st + j];
            a0 += __half2float(tmp[(size_t)s * OUT_F + c]);
        }
        for (int e2 = 0; e2 < novf; ++e2) {        // ~always empty
            if (ovf[2 * e2 + 1] == node)
                a0 += __half2float(tmp[(size_t)ovf[2 * e2] * OUT_F + c]);
        }

        float dg = (float)(cnt + in_cnt[node]);
        float sc = rsqrtf(fmaxf(dg, 1.0f));
        out[(size_t)node * OUT_F + c] = (a0 + a1 + a2 + a3) * sc;
    }
}

// ---------------------------------------------------------------------------
// Fallback path (ws too small): degree + scaled-linear + atomic scatter.
// ---------------------------------------------------------------------------
__global__ void degree_kernel(const int* __restrict__ src, const int* __restrict__ dst,
                              int* __restrict__ out_cnt, int* __restrict__ in_cnt,
                              int n_edges) {
    int i = blockIdx.x * blockDim.x + threadIdx.x;
    if (i < n_edges) {
        atomicAdd(&out_cnt[src[i]], 1);
        atomicAdd(&in_cnt[dst[i]], 1);
    }
}

__global__ __launch_bounds__(256) void linear_fb(const float* __restrict__ feat,
                                                 const float* __restrict__ weight,
                                                 const int* __restrict__ out_cnt,
                                                 __half* __restrict__ tmp, int n_nodes) {
    __shared__ float w[IN_F * OUT_F];
    {
        const float4* wg = (const float4*)weight;
        float4* wsh = (float4*)w;
        for (int i = threadIdx.x; i < IN_F * OUT_F / 4; i += 256) wsh[i] = wg[i];
    }
    __syncthreads();
    int q  = threadIdx.x >> 3;
    int cg = threadIdx.x & 7;
    int row0 = blockIdx.x * 128 + q * 4;
    if (row0 >= n_nodes) return;
    int rmax = n_nodes - row0;
    if (rmax > 4) rmax = 4;
    const float4* feat4 = (const float4*)feat;
    float4 acc[4];
#pragma unroll
    for (int r = 0; r < 4; ++r) acc[r] = make_float4(0.f, 0.f, 0.f, 0.f);
    for (int k4 = 0; k4 < IN_F / 4; ++k4) {
        float4 wv0 = *(const float4*)&w[(4 * k4 + 0) * OUT_F + 4 * cg];
        float4 wv1 = *(const float4*)&w[(4 * k4 + 1) * OUT_F + 4 * cg];
        float4 wv2 = *(const float4*)&w[(4 * k4 + 2) * OUT_F + 4 * cg];
        float4 wv3 = *(const float4*)&w[(4 * k4 + 3) * OUT_F + 4 * cg];
#pragma unroll
        for (int r = 0; r < 4; ++r) {
            int rr = (r < rmax) ? r : 0;
            float4 f = feat4[(size_t)(row0 + rr) * (IN_F / 4) + k4];
            acc[r].x += f.x * wv0.x + f.y * wv1.x + f.z * wv2.x + f.w * wv3.x;
            acc[r].y += f.x * wv0.y + f.y * wv1.y + f.z * wv2.y + f.w * wv3.y;
            acc[r].z += f.x * wv0.z + f.y * wv1.z + f.z * wv2.z + f.w * wv3.z;
            acc[r].w += f.x * wv0.w + f.y * wv1.w + f.z * wv2.w + f.w * wv3.w;
        }
    }
#pragma unroll
    for (int r = 0; r < 4; ++r) {
        if (r < rmax) {
            float sc = rsqrtf(fmaxf((float)out_cnt[row0 + r], 1.0f));
            union { __half h[4]; uint2 u; } pk;
            pk.h[0] = __float2half(acc[r].x * sc);
            pk.h[1] = __float2half(acc[r].y * sc);
            pk.h[2] = __float2half(acc[r].z * sc);
            pk.h[3] = __float2half(acc[r].w * sc);
            *(uint2*)&tmp[(size_t)(row0 + r) * OUT_F + 4 * cg] = pk.u;
        }
    }
}

__global__ void scatter_kernel(const int* __restrict__ src, const int* __restrict__ dst,
                               const __half* __restrict__ tmp, float* __restrict__ out,
                               int n_edges) {
    long long t = (long long)blockIdx.x * blockDim.x + threadIdx.x;
    int e = (int)(t >> 5);
    int c = (int)(t & (OUT_F - 1));
    if (e < n_edges) {
        atomicAdd(&out[(size_t)dst[e] * OUT_F + c],
                  __half2float(tmp[(size_t)src[e] * OUT_F + c]));
    }
}

__global__ void finalize_kernel(float* __restrict__ out, const int* __restrict__ in_cnt,
                                int n_total) {
    int t = blockIdx.x * blockDim.x + threadIdx.x;
    if (t < n_total) {
        out[t] *= rsqrtf(fmaxf((float)in_cnt[t >> 5], 1.0f));
    }
}

extern "C" void kernel_launch(void* const* d_in, const int* in_sizes, int n_in,
                              void* d_out, int out_size, void* d_ws, size_t ws_size,
                              hipStream_t stream) {
    const float* feat   = (const float*)d_in[0];
    const int*   src    = (const int*)d_in[1];
    const int*   dst    = (const int*)d_in[2];
    const float* weight = (const float*)d_in[3];
    float*       out    = (float*)d_out;

    int n_nodes = in_sizes[0] / IN_F;   // 100000
    int n_edges = in_sizes[1];          // 1600000
    int n_buckets = (n_nodes + R_NODES - 1) / R_NODES;  // 391 (<= MAXNB)

    // ws layout: [out_cnt n][in_cnt n][gcur MAXNB][ovf_cnt 8][ovf 2*CAP]
    //            [bkt nb*BKT_CAP][tmp fp16 n*32]
    int*      out_cnt = (int*)d_ws;
    int*      in_cnt  = out_cnt + n_nodes;
    int*      gcur    = in_cnt + n_nodes;
    int*      ovf_cnt = gcur + MAXNB;
    int*      ovf     = ovf_cnt + 8;
    unsigned* bkt     = (unsigned*)(ovf + 2 * OVF_CAP);
    __half*   tmp     = (__half*)(bkt + (size_t)n_buckets * BKT_CAP);
    size_t    needed  = (char*)(tmp + (size_t)n_nodes * OUT_F) - (char*)d_ws;

    if (ws_size >= needed && n_buckets <= MAXNB) {
        hipMemsetAsync(out_cnt, 0, ((size_t)2 * n_nodes + MAXNB + 8) * sizeof(int), stream);
        int n_bbl = (n_edges + EPB - 1) / EPB;          // 196
        int n_lbl = (n_nodes + 511) / 512;              // 196
        int lstart = (n_bbl > 256) ? n_bbl : 256;       // CU-paired layout
        mega_kernel<<<lstart + n_lbl, 1024, 0, stream>>>(
            src, dst, feat, weight, out_cnt, in_cnt, gcur, bkt, ovf, ovf_cnt,
            tmp, n_edges, n_nodes, n_bbl, n_lbl, lstart);
        scale_tmp<<<(n_nodes * 4 + 255) / 256, 256, 0, stream>>>(tmp, out_cnt, n_nodes);
        sortgather_kernel<<<n_buckets, 1024, 0, stream>>>(
            bkt, gcur, in_cnt, ovf, ovf_cnt, tmp, out, n_nodes);
    } else {
        // fallback: atomic scatter
        __half* tmp_fb = (__half*)(ovf + 2 * OVF_CAP);
        hipMemsetAsync(out_cnt, 0, ((size_t)2 * n_nodes + MAXNB + 8) * sizeof(int), stream);
        hipMemsetAsync(d_out, 0, (size_t)out_size * sizeof(float), stream);
        degree_kernel<<<(n_edges + 255) / 256, 256, 0, stream>>>(src, dst, out_cnt, in_cnt, n_edges);
        linear_fb<<<(n_nodes + 127) / 128, 256, 0, stream>>>(feat, weight, out_cnt, tmp_fb, n_nodes);
        long long st = (long long)n_edges * OUT_F;
        scatter_kernel<<<(int)((st + 255) / 256), 256, 0, stream>>>(src, dst, tmp_fb, out, n_edges);
        finalize_kernel<<<(n_nodes * OUT_F + 255) / 256, 256, 0, stream>>>(out, in_cnt, n_nodes * OUT_F);
    }
}